// Round 13
// baseline (67.658 us; speedup 1.0000x reference)
//
#include <hip/hip_runtime.h>
#include <math.h>

#define C2 2.8853900817779268f   // 2*log2(e)

// prep (1024 blocks x 512):
//  blocks 0..511 : ekt[b][t4][g32][k64][hi4] = exp2(C2 * K[b][k=t*64+k64][h=4g+hi])
//  blocks 512..  : eqs[b][q][h]              = exp2(C2 * Q[b][q][h])
__global__ __launch_bounds__(512) void addattn_prep(const float* __restrict__ k_g,
                                                    const float* __restrict__ q_g,
                                                    float* __restrict__ ekt,
                                                    float* __restrict__ eqs)
{
    if (blockIdx.x < 512) {
        int tid = blockIdx.x * 512 + threadIdx.x;   // 262144
        int b   = tid >> 13;
        int r   = tid & 8191;
        int g   = r >> 8;           // h-chunk of 4 (0..31)
        int k   = r & 255;
        float4 kv = *(const float4*)(k_g + ((size_t)(b * 256 + k)) * 128 + (g << 2));
        float4 E;
        E.x = __builtin_amdgcn_exp2f(C2 * kv.x);
        E.y = __builtin_amdgcn_exp2f(C2 * kv.y);
        E.z = __builtin_amdgcn_exp2f(C2 * kv.z);
        E.w = __builtin_amdgcn_exp2f(C2 * kv.w);
        *(float4*)(ekt + ((size_t)(((b << 2) + (k >> 6)) << 5 | g)) * 256 + ((k & 63) << 2)) = E;
    } else {
        int tid = (blockIdx.x - 512) * 512 + threadIdx.x;   // 262144 float4s
        float4 qv = ((const float4*)q_g)[tid];
        float4 E;
        E.x = __builtin_amdgcn_exp2f(C2 * qv.x);
        E.y = __builtin_amdgcn_exp2f(C2 * qv.y);
        E.z = __builtin_amdgcn_exp2f(C2 * qv.z);
        E.w = __builtin_amdgcn_exp2f(C2 * qv.w);
        ((float4*)eqs)[tid] = E;
    }
}

// main: 1024 blocks x 512 thr = 524288 threads -> exactly 32 waves/CU.
// Block = 8 q rows. Wave = row-pair rp (2 rows) x k-half kh (128 k).
// 3 barriers: scores->LDS, attn->LDS, PV-partials->LDS.
__global__ __launch_bounds__(512, 8) void addattn_kernel(
    const float* __restrict__ eqs, const float* __restrict__ ekt,
    const float* __restrict__ v_g, const float* __restrict__ w_g,
    float* __restrict__ out)
{
    __shared__ float sblk[2048];   // 8 KB: [8 rows][256] scores
    __shared__ float abuf[2048];   // 8 KB: [8 rows][256] attn
    __shared__ float pbuf[1024];   // 4 KB: [8 rows][128] PV partials (kh=1)

    const int tid  = threadIdx.x;
    const int lane = tid & 63;
    const int wv   = __builtin_amdgcn_readfirstlane(tid >> 6);  // 0..7 uniform
    const int kh   = wv & 1;       // k-half
    const int rp   = wv >> 1;      // row-pair 0..3

    // XCD-grouped remap: each XCD's 128 blocks cover 4 whole batches
    const int o   = ((blockIdx.x & 7) << 7) + (blockIdx.x >> 3);   // 0..1023
    const int b   = o >> 5;
    const int q0  = (o & 31) << 3;       // 8 rows per block
    const int qr0 = q0 + (rp << 1);      // wave's 2 q rows

    const float*  eqg = eqs + (size_t)(b * 256 + qr0) * 128;       // wave-uniform
    const float4* ekp = (const float4*)(ekt + (size_t)b * 32768);

    // ---- score: wave's 2 tiles (t = 2kh, 2kh+1); rational-4 over h ----
    float sc00, sc01, sc10, sc11;    // [tt][row], static names
    #define SCORE_TILE(TT, SA, SB)                                            \
    {                                                                         \
        const int t = (kh << 1) + TT;                                         \
        float s0 = 0.f, s1 = 0.f;                                             \
        _Pragma("unroll 4")                                                   \
        for (int g = 0; g < 32; ++g) {                                        \
            float4 k4 = ekp[((t << 5) + g) * 64 + lane];                      \
            float4 w4 = *(const float4*)(w_g + (g << 2));                     \
            float4 e0 = *(const float4*)(eqg + (g << 2));                     \
            float4 e1 = *(const float4*)(eqg + 128 + (g << 2));               \
            {                                                                 \
                float d0 = fmaf(e0.x, k4.x, 1.f), d1 = fmaf(e0.y, k4.y, 1.f);  \
                float d2 = fmaf(e0.z, k4.z, 1.f), d3 = fmaf(e0.w, k4.w, 1.f);  \
                float P01 = d0 * d1, P23 = d2 * d3;                           \
                float N01 = fmaf(w4.x, d1, w4.y * d0);                        \
                float N23 = fmaf(w4.z, d3, w4.w * d2);                        \
                float num = fmaf(N01, P23, N23 * P01);                        \
                s0 = fmaf(num, __builtin_amdgcn_rcpf(P01 * P23), s0);         \
            }                                                                 \
            {                                                                 \
                float d0 = fmaf(e1.x, k4.x, 1.f), d1 = fmaf(e1.y, k4.y, 1.f);  \
                float d2 = fmaf(e1.z, k4.z, 1.f), d3 = fmaf(e1.w, k4.w, 1.f);  \
                float P01 = d0 * d1, P23 = d2 * d3;                           \
                float N01 = fmaf(w4.x, d1, w4.y * d0);                        \
                float N23 = fmaf(w4.z, d3, w4.w * d2);                        \
                float num = fmaf(N01, P23, N23 * P01);                        \
                s1 = fmaf(num, __builtin_amdgcn_rcpf(P01 * P23), s1);         \
            }                                                                 \
        }                                                                     \
        SA = s0; SB = s1;                                                     \
    }
    SCORE_TILE(0, sc00, sc01)
    SCORE_TILE(1, sc10, sc11)
    #undef SCORE_TILE

    // scores -> sblk (wave's k-half of its 2 rows)
    {
        float* s0 = sblk + ((rp << 1) + 0) * 256 + (kh << 7);
        float* s1 = sblk + ((rp << 1) + 1) * 256 + (kh << 7);
        s0[lane]      = -C2 * sc00;
        s0[64 + lane] = -C2 * sc10;
        s1[lane]      = -C2 * sc01;
        s1[64 + lane] = -C2 * sc11;
    }
    __syncthreads();

    // ---- softmax: each wave does its 2 rows over full 256 (partner-duplicated) ----
    #pragma unroll
    for (int r = 0; r < 2; ++r) {
        const float* sr = sblk + ((rp << 1) + r) * 256;
        float4 sv = *(const float4*)(sr + (lane << 2));     // k = 4*lane..+3
        float m = fmaxf(fmaxf(sv.x, sv.y), fmaxf(sv.z, sv.w));
        #pragma unroll
        for (int off = 32; off; off >>= 1) m = fmaxf(m, __shfl_xor(m, off));
        float e0 = __builtin_amdgcn_exp2f(sv.x - m);
        float e1 = __builtin_amdgcn_exp2f(sv.y - m);
        float e2 = __builtin_amdgcn_exp2f(sv.z - m);
        float e3 = __builtin_amdgcn_exp2f(sv.w - m);
        float sum = (e0 + e1) + (e2 + e3);
        #pragma unroll
        for (int off = 32; off; off >>= 1) sum += __shfl_xor(sum, off);
        float inv = __builtin_amdgcn_rcpf(sum);
        float4 at; at.x = e0 * inv; at.y = e1 * inv; at.z = e2 * inv; at.w = e3 * inv;
        // partner waves write identical values -> benign
        *(float4*)(abuf + ((rp << 1) + r) * 256 + (lane << 2)) = at;
    }
    __syncthreads();

    // ---- PV: wave covers its k-half; lane = h-pair (h = 2*lane, 2*lane+1) ----
    float2 o0, o1;
    o0.x = o0.y = o1.x = o1.y = 0.f;
    {
        const float2* vp = (const float2*)(v_g + (size_t)b * 32768) + (kh << 13) + lane;
        const float* ar0 = abuf + ((rp << 1) + 0) * 256 + (kh << 7);
        const float* ar1 = abuf + ((rp << 1) + 1) * 256 + (kh << 7);
        #pragma unroll 4
        for (int j4 = 0; j4 < 32; ++j4) {
            float4 a0 = *(const float4*)(ar0 + (j4 << 2));    // broadcast
            float4 a1 = *(const float4*)(ar1 + (j4 << 2));
            #pragma unroll
            for (int i = 0; i < 4; ++i) {
                float2 v2 = vp[((j4 << 2) + i) << 6];         // 512B coalesced
                float c0 = (&a0.x)[i], c1 = (&a1.x)[i];
                o0.x = fmaf(c0, v2.x, o0.x); o0.y = fmaf(c0, v2.y, o0.y);
                o1.x = fmaf(c1, v2.x, o1.x); o1.y = fmaf(c1, v2.y, o1.y);
            }
        }
    }

    // ---- combine k-halves via LDS partials ----
    if (kh == 1) {
        *(float2*)(pbuf + ((rp << 1) + 0) * 128 + (lane << 1)) = o0;
        *(float2*)(pbuf + ((rp << 1) + 1) * 128 + (lane << 1)) = o1;
    }
    __syncthreads();
    if (kh == 0) {
        float2 p0 = *(const float2*)(pbuf + ((rp << 1) + 0) * 128 + (lane << 1));
        float2 p1 = *(const float2*)(pbuf + ((rp << 1) + 1) * 128 + (lane << 1));
        o0.x += p0.x; o0.y += p0.y;
        o1.x += p1.x; o1.y += p1.y;
        float* ob = out + (size_t)(b * 256 + qr0) * 128 + (lane << 1);
        *(float2*)(ob)       = o0;
        *(float2*)(ob + 128) = o1;
    }
}

extern "C" void kernel_launch(void* const* d_in, const int* in_sizes, int n_in,
                              void* d_out, int out_size, void* d_ws, size_t ws_size,
                              hipStream_t stream) {
    const float* q = (const float*)d_in[0];
    const float* k = (const float*)d_in[1];
    const float* v = (const float*)d_in[2];
    const float* w = (const float*)d_in[3];
    float* out = (float*)d_out;
    float* ekt = (float*)d_ws;                         // 4 MB
    float* eqs = (float*)d_ws + (32 * 256 * 128);      // 4 MB (ws >= 8 MB)
    addattn_prep<<<1024, 512, 0, stream>>>(k, q, ekt, eqs);
    addattn_kernel<<<1024, 512, 0, stream>>>(eqs, ekt, v, w, out);
}

// Round 14
// 60.644 us; speedup vs baseline: 1.1157x; 1.1157x over previous
//
#include <hip/hip_runtime.h>
#include <math.h>

#define C2 2.8853900817779268f   // 2*log2(e)

// prep (1024 blocks x 512):
//  blocks 0..511 : ekt[b][t4][g32][k64][hi4] = exp2(C2 * K[b][k=t*64+k64][h=4g+hi])
//  blocks 512..  : eqs[b][q][h]              = exp2(C2 * Q[b][q][h])
__global__ __launch_bounds__(512) void addattn_prep(const float* __restrict__ k_g,
                                                    const float* __restrict__ q_g,
                                                    float* __restrict__ ekt,
                                                    float* __restrict__ eqs)
{
    if (blockIdx.x < 512) {
        int tid = blockIdx.x * 512 + threadIdx.x;   // 262144
        int b   = tid >> 13;
        int r   = tid & 8191;
        int g   = r >> 8;           // h-chunk of 4 (0..31)
        int k   = r & 255;
        float4 kv = *(const float4*)(k_g + ((size_t)(b * 256 + k)) * 128 + (g << 2));
        float4 E;
        E.x = __builtin_amdgcn_exp2f(C2 * kv.x);
        E.y = __builtin_amdgcn_exp2f(C2 * kv.y);
        E.z = __builtin_amdgcn_exp2f(C2 * kv.z);
        E.w = __builtin_amdgcn_exp2f(C2 * kv.w);
        *(float4*)(ekt + ((size_t)(((b << 2) + (k >> 6)) << 5 | g)) * 256 + ((k & 63) << 2)) = E;
    } else {
        int tid = (blockIdx.x - 512) * 512 + threadIdx.x;   // 262144 float4s
        float4 qv = ((const float4*)q_g)[tid];
        float4 E;
        E.x = __builtin_amdgcn_exp2f(C2 * qv.x);
        E.y = __builtin_amdgcn_exp2f(C2 * qv.y);
        E.z = __builtin_amdgcn_exp2f(C2 * qv.z);
        E.w = __builtin_amdgcn_exp2f(C2 * qv.w);
        ((float4*)eqs)[tid] = E;
    }
}

// main: 512 blocks x 512 thr (8 waves), wave = 2 q rows, block = 16 rows.
// Score: k4 from single-buffered 64-k LDS tiles (staged once per block, T14
// reg-prefetch); Eq/w via wave-uniform scalar loads. PV: r12's (attn LDS
// broadcast, V global). 2 barriers per tile, 4 tiles.
__global__ __launch_bounds__(512, 4) void addattn_kernel(
    const float* __restrict__ eqs, const float* __restrict__ ekt,
    const float* __restrict__ v_g, const float* __restrict__ w_g,
    float* __restrict__ out)
{
    __shared__ float kbuf[8192];    // 32 KB: one 64-k tile [g32][k64][hi4]
    __shared__ float sattn[4096];   // 16 KB: 8 waves x [2 rows][256] attn

    const int tid  = threadIdx.x;
    const int lane = tid & 63;
    const int wv   = __builtin_amdgcn_readfirstlane(tid >> 6);  // 0..7 uniform

    // XCD-grouped remap: 4 whole batches per XCD -> ekt/V L2-hot
    const int o   = ((blockIdx.x & 7) << 6) + (blockIdx.x >> 3);
    const int b   = o >> 4;
    const int q0  = (o & 15) << 4;
    const int qr0 = q0 + (wv << 1);   // wave's 2 q rows

    const float*  eqg = eqs + (size_t)(b * 256 + qr0) * 128;       // wave-uniform
    const float4* ekp = (const float4*)(ekt + (size_t)b * 32768);  // [t][g][k64][hi]

    // prefetch tile 0 into regs
    float4 p0 = ekp[tid], p1 = ekp[tid + 512], p2 = ekp[tid + 1024], p3 = ekp[tid + 1536];

    float sc[4][2];
    #pragma unroll
    for (int t = 0; t < 4; ++t) {
        __syncthreads();                       // prev tile's compute done
        ((float4*)kbuf)[tid]        = p0;      // 2048 float4 = 32 KB, linear
        ((float4*)kbuf)[tid + 512]  = p1;
        ((float4*)kbuf)[tid + 1024] = p2;
        ((float4*)kbuf)[tid + 1536] = p3;
        __syncthreads();                       // tile t visible
        if (t < 3) {                           // T14: issue next tile early
            p0 = ekp[((t + 1) << 11) + tid];
            p1 = ekp[((t + 1) << 11) + 512 + tid];
            p2 = ekp[((t + 1) << 11) + 1024 + tid];
            p3 = ekp[((t + 1) << 11) + 1536 + tid];
        }
        float s0 = 0.f, s1 = 0.f;
        #pragma unroll 4
        for (int g = 0; g < 32; ++g) {
            float4 k4 = *(const float4*)&kbuf[(g << 8) + (lane << 2)];  // b128, conflict-free
            float4 w4 = *(const float4*)(w_g + (g << 2));               // s_load
            float4 e0 = *(const float4*)(eqg + (g << 2));               // s_load
            float4 e1 = *(const float4*)(eqg + 128 + (g << 2));         // s_load
            {
                float d0 = fmaf(e0.x, k4.x, 1.f), d1 = fmaf(e0.y, k4.y, 1.f);
                float d2 = fmaf(e0.z, k4.z, 1.f), d3 = fmaf(e0.w, k4.w, 1.f);
                float P01 = d0 * d1, P23 = d2 * d3;
                float N01 = fmaf(w4.x, d1, w4.y * d0);
                float N23 = fmaf(w4.z, d3, w4.w * d2);
                float num = fmaf(N01, P23, N23 * P01);
                s0 = fmaf(num, __builtin_amdgcn_rcpf(P01 * P23), s0);
            }
            {
                float d0 = fmaf(e1.x, k4.x, 1.f), d1 = fmaf(e1.y, k4.y, 1.f);
                float d2 = fmaf(e1.z, k4.z, 1.f), d3 = fmaf(e1.w, k4.w, 1.f);
                float P01 = d0 * d1, P23 = d2 * d3;
                float N01 = fmaf(w4.x, d1, w4.y * d0);
                float N23 = fmaf(w4.z, d3, w4.w * d2);
                float num = fmaf(N01, P23, N23 * P01);
                s1 = fmaf(num, __builtin_amdgcn_rcpf(P01 * P23), s1);
            }
        }
        sc[t][0] = s0; sc[t][1] = s1;
    }

    // ---- softmax per row, in registers (lane holds k = 64t+lane) ----
    float* strip = sattn + (wv << 9);    // [r*256 + k]
    #pragma unroll
    for (int r = 0; r < 2; ++r) {
        float x0 = -C2 * sc[0][r], x1 = -C2 * sc[1][r];
        float x2 = -C2 * sc[2][r], x3 = -C2 * sc[3][r];
        float m = fmaxf(fmaxf(x0, x1), fmaxf(x2, x3));
        #pragma unroll
        for (int off = 32; off; off >>= 1) m = fmaxf(m, __shfl_xor(m, off));
        float e0 = __builtin_amdgcn_exp2f(x0 - m);
        float e1 = __builtin_amdgcn_exp2f(x1 - m);
        float e2 = __builtin_amdgcn_exp2f(x2 - m);
        float e3 = __builtin_amdgcn_exp2f(x3 - m);
        float sum = (e0 + e1) + (e2 + e3);
        #pragma unroll
        for (int off = 32; off; off >>= 1) sum += __shfl_xor(sum, off);
        float inv = __builtin_amdgcn_rcpf(sum);
        strip[(r << 8) + lane]       = e0 * inv;   // same-wave ds ordering, no barrier
        strip[(r << 8) + 64 + lane]  = e1 * inv;
        strip[(r << 8) + 128 + lane] = e2 * inv;
        strip[(r << 8) + 192 + lane] = e3 * inv;
    }

    // ---- PV: lane = h-pair (h = 2*lane, 2*lane+1); attn via LDS float4 bcast ----
    float2 o0, o1;
    o0.x = o0.y = o1.x = o1.y = 0.f;
    const float2* vp = (const float2*)(v_g + (size_t)b * 32768) + lane;   // + k*64
    #pragma unroll 8
    for (int j4 = 0; j4 < 64; ++j4) {
        float4 a0 = *(const float4*)(strip + (j4 << 2));          // row 0 attn bcast
        float4 a1 = *(const float4*)(strip + 256 + (j4 << 2));    // row 1 attn bcast
        #pragma unroll
        for (int i = 0; i < 4; ++i) {
            float2 v2 = vp[((j4 << 2) + i) << 6];                 // 512B coalesced
            float c0 = (&a0.x)[i], c1 = (&a1.x)[i];
            o0.x = fmaf(c0, v2.x, o0.x); o0.y = fmaf(c0, v2.y, o0.y);
            o1.x = fmaf(c1, v2.x, o1.x); o1.y = fmaf(c1, v2.y, o1.y);
        }
    }

    float* ob = out + (size_t)(b * 256 + qr0) * 128 + (lane << 1);
    *(float2*)(ob)       = o0;
    *(float2*)(ob + 128) = o1;
}

extern "C" void kernel_launch(void* const* d_in, const int* in_sizes, int n_in,
                              void* d_out, int out_size, void* d_ws, size_t ws_size,
                              hipStream_t stream) {
    const float* q = (const float*)d_in[0];
    const float* k = (const float*)d_in[1];
    const float* v = (const float*)d_in[2];
    const float* w = (const float*)d_in[3];
    float* out = (float*)d_out;
    float* ekt = (float*)d_ws;                         // 4 MB
    float* eqs = (float*)d_ws + (32 * 256 * 128);      // 4 MB (ws >= 8 MB)
    addattn_prep<<<1024, 512, 0, stream>>>(k, q, ekt, eqs);
    addattn_kernel<<<512, 512, 0, stream>>>(eqs, ekt, v, w, out);
}